// Round 3
// baseline (548.747 us; speedup 1.0000x reference)
//
#include <hip/hip_runtime.h>
#include <stdint.h>

typedef short  bf16x8 __attribute__((ext_vector_type(8)));
typedef float  f32x4  __attribute__((ext_vector_type(4)));

// ---------------- common helpers ----------------

__device__ __forceinline__ short f2bf(float f) {
    uint32_t u = __builtin_bit_cast(uint32_t, f);
    u += 0x7FFFu + ((u >> 16) & 1u);          // RNE to bf16
    return (short)(u >> 16);
}

// u[g][s] = COMP[INV[g]][s] for p4m (verified by rounds 1-2 passing)
__device__ __forceinline__ int u_index(int g, int s) {
    int r  = g & 3, m  = g >> 2;
    int r2 = s & 3, ms = s >> 2;
    if (!m) { int rr = (r2 - r) & 3; return ms ? (4 + rr) : rr; }
    else    { int rr = (r - r2) & 3; return ms ? rr : (4 + rr); }
}

// async global->LDS, 16B per lane (LDS dest wave-uniform, HW adds lane*16)
__device__ __forceinline__ void gload_lds16(const void* g, void* l) {
    __builtin_amdgcn_global_load_lds(
        (const __attribute__((address_space(1))) uint32_t*)g,
        (__attribute__((address_space(3))) uint32_t*)l, 16, 0, 0);
}

// ---------------- workspace layout ----------------
// xb  : bf16 [16][66][66][512]   zero-padded NHWC input
// bank: bf16 [9][16][4][512][8]  transformed weights, fragment-ordered
#define XB_BYTES  (16LL * 66 * 66 * 512 * 2)
#define BK_BYTES  (9LL * 16 * 4 * 512 * 8 * 2)
#define WS_NEEDED (XB_BYTES + BK_BYTES)

// ---------------- prep kernels ----------------

// Coalesced NCHW fp32 -> padded NHWC bf16, via LDS transpose.
// grid (64 h, 8 kchunk, 16 b), block 256. Each block: 64 k x 64 w of one row.
__global__ __launch_bounds__(256) void prep_x2(const float* __restrict__ x,
                                               short* __restrict__ xb) {
    __shared__ float t[64][65];               // pad 65: (k+w)%32 -> 2-way max
    const int h = blockIdx.x, kc8 = blockIdx.y, b = blockIdx.z;
    const int k0 = kc8 * 64;
    const int tid = threadIdx.x;
    const int w  = tid & 63, kq = tid >> 6;
    const float* xp = x + ((size_t)(b * 512 + k0 + kq) * 4096) + h * 64 + w;
    #pragma unroll
    for (int i = 0; i < 16; ++i)              // k = k0 + kq + 4i, coalesced in w
        t[kq + 4 * i][w] = xp[(size_t)(4 * i) * 4096];
    __syncthreads();
    const int w2 = tid >> 3, kk = tid & 7;
    #pragma unroll
    for (int half = 0; half < 2; ++half) {
        const int ww = w2 + 32 * half;
        bf16x8 v;
        #pragma unroll
        for (int j = 0; j < 8; ++j) v[j] = f2bf(t[kk * 8 + j][ww]);
        size_t o = (((size_t)b * 66 + h + 1) * 66 + (ww + 1)) * 512 + k0 + kk * 8;
        *reinterpret_cast<bf16x8*>(&xb[o]) = v;
    }
}

// zero the 1-px border of the padded NHWC buffer (replaces 71MB memset)
__global__ __launch_bounds__(256) void zero_border(short* __restrict__ xb) {
    int idx = blockIdx.x * 256 + threadIdx.x;      // 16*260*64 = 266240
    if (idx >= 16 * 260 * 64) return;
    int kg = idx & 63;
    int rest = idx >> 6;
    int b  = rest / 260;
    int pe = rest - b * 260;
    int hh, ww;
    if      (pe < 66)  { hh = 0;            ww = pe; }
    else if (pe < 132) { hh = 65;           ww = pe - 66; }
    else if (pe < 196) { hh = pe - 132 + 1; ww = 0; }
    else               { hh = pe - 196 + 1; ww = 65; }
    size_t o = (((size_t)b * 66 + hh) * 66 + ww) * 512 + kg * 8;
    bf16x8 z = {0,0,0,0,0,0,0,0};
    *reinterpret_cast<bf16x8*>(&xb[o]) = z;
}

// wrel fp32 [64][64][8][3][3] -> bank bf16 [t][kc][kg][oc][8]
__global__ __launch_bounds__(256) void prep_w(const float* __restrict__ wrel,
                                              short* __restrict__ bank) {
    int tg = blockIdx.x * 256 + threadIdx.x;    // 9*16*4*512 = 294912
    int oc = tg & 511;
    int r1 = tg >> 9;
    int kg = r1 & 3;
    int r2 = r1 >> 2;
    int kc = r2 & 15;
    int t  = r2 >> 4;
    int ki = t / 3, kj = t - ki * 3;
    int g = oc & 7, co = oc >> 3;
    int r = g & 3, m = g >> 2;
    int a0, b0;
    switch (r) {
        case 0:  a0 = ki;     b0 = kj;     break;
        case 1:  a0 = kj;     b0 = 2 - ki; break;
        case 2:  a0 = 2 - ki; b0 = 2 - kj; break;
        default: a0 = 2 - kj; b0 = ki;     break;
    }
    if (m) b0 = 2 - b0;
    int ci = kc * 4 + kg;
    const float* wp = wrel + (size_t)(co * 64 + ci) * 72 + a0 * 3 + b0;
    bf16x8 v;
    #pragma unroll
    for (int j = 0; j < 8; ++j) v[j] = f2bf(wp[u_index(g, j) * 9]);
    *reinterpret_cast<bf16x8*>(&bank[(size_t)tg * 8]) = v;
}

// ---------------- main MFMA kernel ----------------
// block: 64 oc x 512 px (16x32 spatial tile), 4 waves; each wave 64oc x 128px
// (4 rows x 32 cols). K-loop: 16 chunks of 32 channels x 9 taps.
__global__ __launch_bounds__(256, 2) void gconv_mfma(
    const short* __restrict__ xb, const short* __restrict__ bank,
    const float* __restrict__ bias, float* __restrict__ out)
{
    // xs : [kg 4][px 640 (used 612 = 18r x 34c)][8k]   40960 B
    // wsm: [t 9][kg 4][oc 64][8k]                       36864 B
    __shared__ __attribute__((aligned(16))) short xs[4 * 640 * 8];
    __shared__ __attribute__((aligned(16))) short wsm[9 * 4 * 64 * 8];

    const int st  = blockIdx.x;           // 8 spatial tiles (4h x 2w)
    const int ot  = blockIdx.y;           // 8 oc tiles
    const int b   = blockIdx.z;           // 16 batches
    const int h0  = (st >> 1) * 16;
    const int w0  = (st & 1) * 32;
    const int oc0 = ot * 64;

    const int tid  = threadIdx.x;
    const int lane = tid & 63;
    const int wid  = tid >> 6;
    const int l15  = lane & 15;
    const int lkg  = lane >> 4;

    f32x4 acc[4][8];
    #pragma unroll
    for (int i = 0; i < 4; ++i)
        #pragma unroll
        for (int j = 0; j < 8; ++j)
            #pragma unroll
            for (int e = 0; e < 4; ++e) acc[i][j][e] = 0.f;

    const int xrow_base = (b * 66 + h0) * 66 + w0;   // padded coords

    // precompute per-thread global element offsets (32-bit, xb < 36M elems)
    int xoff[10];
    #pragma unroll
    for (int q = 0; q < 10; ++q) {
        int it  = wid + 4 * q;            // 0..39
        int kg  = it / 10;
        int sub = it - kg * 10;
        int px  = sub * 64 + lane;        // 0..639
        px = px < 612 ? px : 611;         // pad slots -> harmless dup
        int r = px / 34;
        int c = px - r * 34;
        xoff[q] = (xrow_base + r * 66 + c) * 512 + kg * 8;
    }
    int woff[9];
    #pragma unroll
    for (int q = 0; q < 9; ++q) {
        int it = wid + 4 * q;             // 0..35
        int t  = it >> 2, kg = it & 3;
        woff[q] = ((t * 16) * 4 + kg) * 512 * 8 + (oc0 + lane) * 8;
    }

    for (int kc = 0; kc < 16; ++kc) {
        __syncthreads();

        // ---- stage weights: 36 slots (9 wave-iters) ----
        #pragma unroll
        for (int q = 0; q < 9; ++q) {
            int it = wid + 4 * q;
            gload_lds16(bank + (size_t)woff[q] + kc * 4 * 512 * 8,
                        &wsm[it * 512]);
        }
        // ---- stage x tile: 40 slots (10 wave-iters) ----
        #pragma unroll
        for (int q = 0; q < 10; ++q) {
            int it = wid + 4 * q;
            gload_lds16(xb + (size_t)xoff[q] + kc * 32, &xs[it * 512]);
        }

        __syncthreads();

        // ---- compute: 9 taps x (4 A-frags, 8 B-frags, 32 MFMAs) ----
        #pragma unroll
        for (int t = 0; t < 9; ++t) {
            const int ki = t / 3, kj = t - (t / 3) * 3;
            bf16x8 a[4];
            #pragma unroll
            for (int mi = 0; mi < 4; ++mi)
                a[mi] = *reinterpret_cast<const bf16x8*>(
                    &wsm[((t * 4 + lkg) * 64 + mi * 16 + l15) * 8]);
            #pragma unroll
            for (int nj = 0; nj < 8; ++nj) {
                const int row = wid * 4 + (nj & 3) + ki;
                const int col = (nj >> 2) * 16 + l15 + kj;
                bf16x8 bv = *reinterpret_cast<const bf16x8*>(
                    &xs[(lkg * 640 + row * 34 + col) * 8]);
                #pragma unroll
                for (int mi = 0; mi < 4; ++mi)
                    acc[mi][nj] = __builtin_amdgcn_mfma_f32_16x16x32_bf16(
                        a[mi], bv, acc[mi][nj], 0, 0, 0);
            }
        }
    }

    // ---- epilogue: D row=(lane>>4)*4+reg -> oc, col=lane&15 -> pixel ----
    #pragma unroll
    for (int mi = 0; mi < 4; ++mi) {
        #pragma unroll
        for (int j = 0; j < 4; ++j) {
            const int oc_g = oc0 + mi * 16 + lkg * 4 + j;
            const float bv = bias[oc_g >> 3];
            float* op = out + ((size_t)b * 512 + oc_g) * 4096;
            #pragma unroll
            for (int nj = 0; nj < 8; ++nj) {
                const int hh = h0 + wid * 4 + (nj & 3);
                const int wwp = w0 + (nj >> 2) * 16 + l15;
                op[hh * 64 + wwp] = acc[mi][nj][j] + bv;
            }
        }
    }
}

// ---------------- fp32 fallback (ws too small; verified round 1) ----------
__global__ __launch_bounds__(256) void gconv_direct(
    const float* __restrict__ x, const float* __restrict__ wrel,
    const float* __restrict__ bias, float* __restrict__ out)
{
    __shared__ float xsf[18][20];
    __shared__ float wsf[16][9];
    const int st = blockIdx.x, ct = blockIdx.y, b = blockIdx.z;
    const int h0 = (st >> 2) * 16, w0 = (st & 3) * 16, oc0 = ct * 16;
    const int tid = threadIdx.x;
    const int ch = tid & 15, blk = tid >> 4;
    const int by = (blk >> 2) * 4, bx = (blk & 3) * 4;
    const int oc = oc0 + ch, g = oc & 7, co = oc >> 3;
    const int wl_c = tid / 9, wl_k = tid - wl_c * 9;
    const int wl_i = wl_k / 3, wl_j = wl_k - wl_i * 3;
    const int wl_oc = oc0 + wl_c, wl_g = wl_oc & 7, wl_co = wl_oc >> 3;
    int a0, b0;
    { const int r = wl_g & 3, m = wl_g >> 2;
      switch (r) { case 0: a0=wl_i; b0=wl_j; break; case 1: a0=wl_j; b0=2-wl_i; break;
                   case 2: a0=2-wl_i; b0=2-wl_j; break; default: a0=2-wl_j; b0=wl_i; break; }
      if (m) b0 = 2 - b0; }
    float acc[4][4];
    #pragma unroll
    for (int i=0;i<4;++i) for (int j=0;j<4;++j) acc[i][j]=0.f;
    for (int t = 0; t < 512; ++t) {
        const int ci = t >> 3, s = t & 7;
        __syncthreads();
        const float* xp = x + (((size_t)(b * 64 + ci) * 8 + s) * 4096);
        for (int idx = tid; idx < 18 * 18; idx += 256) {
            const int rr = idx / 18, cc = idx - rr * 18;
            const int gh = h0 - 1 + rr, gw = w0 - 1 + cc;
            float v = 0.f;
            if (gh >= 0 && gh < 64 && gw >= 0 && gw < 64) v = xp[gh * 64 + gw];
            xsf[rr][cc] = v;
        }
        if (tid < 144) {
            const int u = u_index(wl_g, s);
            wsf[wl_c][wl_k] = wrel[((size_t)(wl_co*64+ci)*8+u)*9 + a0*3 + b0];
        }
        __syncthreads();
        float wr[9];
        #pragma unroll
        for (int k=0;k<9;++k) wr[k]=wsf[ch][k];
        float xv[6][6];
        #pragma unroll
        for (int i=0;i<6;++i) for (int j=0;j<6;++j) xv[i][j]=xsf[by+i][bx+j];
        #pragma unroll
        for (int py=0;py<4;++py) for (int px=0;px<4;++px)
            for (int ki=0;ki<3;++ki) for (int kj=0;kj<3;++kj)
                acc[py][px] += xv[py+ki][px+kj]*wr[ki*3+kj];
    }
    const float bv = bias[co];
    float* op = out + (((size_t)(b*64+co)*8+g)*4096);
    #pragma unroll
    for (int py=0;py<4;++py) for (int px=0;px<4;++px)
        op[(h0+by+py)*64 + (w0+bx+px)] = acc[py][px] + bv;
}

// ---------------- launch ----------------
extern "C" void kernel_launch(void* const* d_in, const int* in_sizes, int n_in,
                              void* d_out, int out_size, void* d_ws, size_t ws_size,
                              hipStream_t stream) {
    const float* x    = (const float*)d_in[0];
    const float* wrel = (const float*)d_in[1];
    const float* bias = (const float*)d_in[2];
    float* out        = (float*)d_out;

    if (ws_size >= (size_t)WS_NEEDED) {
        short* xb   = (short*)d_ws;
        short* bank = (short*)((char*)d_ws + XB_BYTES);
        zero_border<<<1040, 256, 0, stream>>>(xb);
        {
            dim3 g(64, 8, 16);
            prep_x2<<<g, 256, 0, stream>>>(x, xb);
        }
        prep_w<<<1152, 256, 0, stream>>>(wrel, bank);
        dim3 grid(8, 8, 16);
        gconv_mfma<<<grid, 256, 0, stream>>>(xb, bank, bias, out);
    } else {
        dim3 grid(16, 32, 16);
        gconv_direct<<<grid, 256, 0, stream>>>(x, wrel, bias, out);
    }
}

// Round 4
// 327.498 us; speedup vs baseline: 1.6756x; 1.6756x over previous
//
#include <hip/hip_runtime.h>
#include <stdint.h>

typedef short  bf16x8 __attribute__((ext_vector_type(8)));
typedef float  f32x4  __attribute__((ext_vector_type(4)));

// ---------------- common helpers ----------------

__device__ __forceinline__ short f2bf(float f) {
    uint32_t u = __builtin_bit_cast(uint32_t, f);
    u += 0x7FFFu + ((u >> 16) & 1u);          // RNE to bf16
    return (short)(u >> 16);
}

// u[g][s] = COMP[INV[g]][s] for p4m (verified by rounds 1-3 passing)
__device__ __forceinline__ int u_index(int g, int s) {
    int r  = g & 3, m  = g >> 2;
    int r2 = s & 3, ms = s >> 2;
    if (!m) { int rr = (r2 - r) & 3; return ms ? (4 + rr) : rr; }
    else    { int rr = (r - r2) & 3; return ms ? rr : (4 + rr); }
}

// async global->LDS, 16B per lane (LDS dest wave-uniform, HW adds lane*16)
__device__ __forceinline__ void gload_lds16(const void* g, void* l) {
    __builtin_amdgcn_global_load_lds(
        (const __attribute__((address_space(1))) uint32_t*)g,
        (__attribute__((address_space(3))) uint32_t*)l, 16, 0, 0);
}

// ---------------- workspace layout ----------------
// xb  : bf16 [16][66][66][512]   zero-padded NHWC input
// bank: bf16 [kc 16][t 9][kg 4][oc 512][8]  transformed weights,
//       fragment-ordered, per-kc contiguous (L2-friendly 295KB slabs)
#define XB_BYTES  (16LL * 66 * 66 * 512 * 2)
#define BK_BYTES  (16LL * 9 * 4 * 512 * 8 * 2)
#define WS_NEEDED (XB_BYTES + BK_BYTES)

// ---------------- prep kernels ----------------

// Coalesced NCHW fp32 -> padded NHWC bf16, via LDS transpose.
__global__ __launch_bounds__(256) void prep_x2(const float* __restrict__ x,
                                               short* __restrict__ xb) {
    __shared__ float t[64][65];
    const int h = blockIdx.x, kc8 = blockIdx.y, b = blockIdx.z;
    const int k0 = kc8 * 64;
    const int tid = threadIdx.x;
    const int w  = tid & 63, kq = tid >> 6;
    const float* xp = x + ((size_t)(b * 512 + k0 + kq) * 4096) + h * 64 + w;
    #pragma unroll
    for (int i = 0; i < 16; ++i)
        t[kq + 4 * i][w] = xp[(size_t)(4 * i) * 4096];
    __syncthreads();
    const int w2 = tid >> 3, kk = tid & 7;
    #pragma unroll
    for (int half = 0; half < 2; ++half) {
        const int ww = w2 + 32 * half;
        bf16x8 v;
        #pragma unroll
        for (int j = 0; j < 8; ++j) v[j] = f2bf(t[kk * 8 + j][ww]);
        size_t o = (((size_t)b * 66 + h + 1) * 66 + (ww + 1)) * 512 + k0 + kk * 8;
        *reinterpret_cast<bf16x8*>(&xb[o]) = v;
    }
}

// zero the 1-px border of the padded NHWC buffer
__global__ __launch_bounds__(256) void zero_border(short* __restrict__ xb) {
    int idx = blockIdx.x * 256 + threadIdx.x;      // 16*260*64 = 266240
    if (idx >= 16 * 260 * 64) return;
    int kg = idx & 63;
    int rest = idx >> 6;
    int b  = rest / 260;
    int pe = rest - b * 260;
    int hh, ww;
    if      (pe < 66)  { hh = 0;            ww = pe; }
    else if (pe < 132) { hh = 65;           ww = pe - 66; }
    else if (pe < 196) { hh = pe - 132 + 1; ww = 0; }
    else               { hh = pe - 196 + 1; ww = 65; }
    size_t o = (((size_t)b * 66 + hh) * 66 + ww) * 512 + kg * 8;
    bf16x8 z = {0,0,0,0,0,0,0,0};
    *reinterpret_cast<bf16x8*>(&xb[o]) = z;
}

// wrel fp32 [64][64][8][3][3] -> bank bf16 [kc][t][kg][oc][8]
__global__ __launch_bounds__(256) void prep_w(const float* __restrict__ wrel,
                                              short* __restrict__ bank) {
    int tg = blockIdx.x * 256 + threadIdx.x;    // 9*16*4*512 = 294912
    int oc = tg & 511;
    int kg = (tg >> 9) & 3;
    int kc = (tg >> 11) & 15;
    int t  = tg >> 15;                          // 0..8
    int ki = t / 3, kj = t - ki * 3;
    int g = oc & 7, co = oc >> 3;
    int r = g & 3, m = g >> 2;
    int a0, b0;
    switch (r) {
        case 0:  a0 = ki;     b0 = kj;     break;
        case 1:  a0 = kj;     b0 = 2 - ki; break;
        case 2:  a0 = 2 - ki; b0 = 2 - kj; break;
        default: a0 = 2 - kj; b0 = ki;     break;
    }
    if (m) b0 = 2 - b0;
    int ci = kc * 4 + kg;
    const float* wp = wrel + (size_t)(co * 64 + ci) * 72 + a0 * 3 + b0;
    bf16x8 v;
    #pragma unroll
    for (int j = 0; j < 8; ++j) v[j] = f2bf(wp[u_index(g, j) * 9]);
    size_t o = ((((size_t)kc * 9 + t) * 4 + kg) * 512 + oc) * 8;
    *reinterpret_cast<bf16x8*>(&bank[o]) = v;
}

// ---------------- main MFMA kernel ----------------
// block: 64 oc x 512 px (16x32 spatial tile), 4 waves; each wave 64oc x 128px.
// Double-buffered LDS (150KB, 1 block/CU): STAGE(kc+1) issued before
// COMPUTE(kc); single vmcnt(0)+barrier per chunk hides global latency.
#define XS_SLOTS 39                 // 39*64 = 2496 >= 4*624 (kg-region 624 px)
#define XS_SH    (XS_SLOTS * 512)   // shorts per x buffer
#define WS_SH    (36 * 512)         // shorts per w buffer

#define STAGE(XS, WS, kc)                                                  \
    {                                                                      \
        _Pragma("unroll")                                                  \
        for (int q = 0; q < 9; ++q) {                                      \
            int it = wid + 4 * q;                                          \
            gload_lds16(bank + (size_t)(kc) * 147456 + woff[q],            \
                        &WS[it * 512]);                                    \
        }                                                                  \
        _Pragma("unroll")                                                  \
        for (int q = 0; q < 10; ++q) {                                     \
            int it = wid + 4 * q;                                          \
            if (it < XS_SLOTS)                                             \
                gload_lds16(xb + (size_t)xoff[q] + (kc) * 32,              \
                            &XS[it * 512]);                                \
        }                                                                  \
    }

#define COMPUTE(XS, WS)                                                    \
    {                                                                      \
        _Pragma("unroll")                                                  \
        for (int t = 0; t < 9; ++t) {                                      \
            const int ki = t / 3, kj = t - (t / 3) * 3;                    \
            bf16x8 a[4];                                                   \
            _Pragma("unroll")                                              \
            for (int mi = 0; mi < 4; ++mi)                                 \
                a[mi] = *reinterpret_cast<const bf16x8*>(                  \
                    &WS[((t * 4 + lkg) * 64 + mi * 16 + l15) * 8]);        \
            _Pragma("unroll")                                              \
            for (int nj = 0; nj < 8; ++nj) {                               \
                const int row = wid * 4 + (nj & 3) + ki;                   \
                const int col = (nj >> 2) * 16 + l15 + kj;                 \
                bf16x8 bv = *reinterpret_cast<const bf16x8*>(              \
                    &XS[(lkg * 624 + row * 34 + col) * 8]);                \
                _Pragma("unroll")                                          \
                for (int mi = 0; mi < 4; ++mi)                             \
                    acc[mi][nj] = __builtin_amdgcn_mfma_f32_16x16x32_bf16( \
                        a[mi], bv, acc[mi][nj], 0, 0, 0);                  \
            }                                                              \
        }                                                                  \
    }

__global__ __launch_bounds__(256, 1) void gconv_mfma(
    const short* __restrict__ xb, const short* __restrict__ bank,
    const float* __restrict__ bias, float* __restrict__ out)
{
    __shared__ __attribute__((aligned(16))) short xsA[XS_SH], xsB[XS_SH];
    __shared__ __attribute__((aligned(16))) short wsA[WS_SH], wsB[WS_SH];

    const int st  = blockIdx.x;           // 8 spatial tiles (4h x 2w)
    const int ot  = blockIdx.y;           // 8 oc tiles
    const int b   = blockIdx.z;           // 16 batches
    const int h0  = (st >> 1) * 16;
    const int w0  = (st & 1) * 32;
    const int oc0 = ot * 64;

    const int tid  = threadIdx.x;
    const int lane = tid & 63;
    const int wid  = tid >> 6;
    const int l15  = lane & 15;
    const int lkg  = lane >> 4;

    f32x4 acc[4][8];
    #pragma unroll
    for (int i = 0; i < 4; ++i)
        #pragma unroll
        for (int j = 0; j < 8; ++j)
            #pragma unroll
            for (int e = 0; e < 4; ++e) acc[i][j][e] = 0.f;

    const int xrow_base = (b * 66 + h0) * 66 + w0;   // padded coords

    // per-thread global element offsets (32-bit ok: xb < 36M elems)
    int xoff[10];
    #pragma unroll
    for (int q = 0; q < 10; ++q) {
        int it = wid + 4 * q;
        if (it >= XS_SLOTS) it = XS_SLOTS - 1;       // unused slot, safe addr
        int slot = it * 64 + lane;                   // < 2496
        int kg = slot / 624;                         // 0..3
        int px = slot - kg * 624;
        px = px < 612 ? px : 611;                    // pad slots -> dup
        int r = px / 34;
        int c = px - r * 34;
        xoff[q] = (xrow_base + r * 66 + c) * 512 + kg * 8;
    }
    int woff[9];
    #pragma unroll
    for (int q = 0; q < 9; ++q) {
        int it = wid + 4 * q;                        // 0..35
        int t  = it >> 2, kg = it & 3;
        woff[q] = ((t * 4 + kg) * 512 + oc0 + lane) * 8;
    }

    // ---- 2-phase double-buffered K-loop (16 chunks of 32 channels) ----
    STAGE(xsA, wsA, 0);
    __syncthreads();
    for (int kc2 = 0; kc2 < 8; ++kc2) {
        STAGE(xsB, wsB, 2 * kc2 + 1);     // prefetch odd chunk
        COMPUTE(xsA, wsA);
        __syncthreads();                  // drains vmcnt -> B ready, A free
        if (kc2 < 7) STAGE(xsA, wsA, 2 * kc2 + 2);
        COMPUTE(xsB, wsB);
        __syncthreads();
    }

    // ---- epilogue: D row=(lane>>4)*4+reg -> oc, col=lane&15 -> pixel ----
    #pragma unroll
    for (int mi = 0; mi < 4; ++mi) {
        #pragma unroll
        for (int j = 0; j < 4; ++j) {
            const int oc_g = oc0 + mi * 16 + lkg * 4 + j;
            const float bv = bias[oc_g >> 3];
            float* op = out + ((size_t)b * 512 + oc_g) * 4096;
            #pragma unroll
            for (int nj = 0; nj < 8; ++nj) {
                const int hh = h0 + wid * 4 + (nj & 3);
                const int wwp = w0 + (nj >> 2) * 16 + l15;
                op[hh * 64 + wwp] = acc[mi][nj][j] + bv;
            }
        }
    }
}

// ---------------- fp32 fallback (ws too small; verified round 1) ----------
__global__ __launch_bounds__(256) void gconv_direct(
    const float* __restrict__ x, const float* __restrict__ wrel,
    const float* __restrict__ bias, float* __restrict__ out)
{
    __shared__ float xsf[18][20];
    __shared__ float wsf[16][9];
    const int st = blockIdx.x, ct = blockIdx.y, b = blockIdx.z;
    const int h0 = (st >> 2) * 16, w0 = (st & 3) * 16, oc0 = ct * 16;
    const int tid = threadIdx.x;
    const int ch = tid & 15, blk = tid >> 4;
    const int by = (blk >> 2) * 4, bx = (blk & 3) * 4;
    const int oc = oc0 + ch, g = oc & 7, co = oc >> 3;
    const int wl_c = tid / 9, wl_k = tid - wl_c * 9;
    const int wl_i = wl_k / 3, wl_j = wl_k - wl_i * 3;
    const int wl_oc = oc0 + wl_c, wl_g = wl_oc & 7, wl_co = wl_oc >> 3;
    int a0, b0;
    { const int r = wl_g & 3, m = wl_g >> 2;
      switch (r) { case 0: a0=wl_i; b0=wl_j; break; case 1: a0=wl_j; b0=2-wl_i; break;
                   case 2: a0=2-wl_i; b0=2-wl_j; break; default: a0=2-wl_j; b0=wl_i; break; }
      if (m) b0 = 2 - b0; }
    float acc[4][4];
    #pragma unroll
    for (int i=0;i<4;++i) for (int j=0;j<4;++j) acc[i][j]=0.f;
    for (int t = 0; t < 512; ++t) {
        const int ci = t >> 3, s = t & 7;
        __syncthreads();
        const float* xp = x + (((size_t)(b * 64 + ci) * 8 + s) * 4096);
        for (int idx = tid; idx < 18 * 18; idx += 256) {
            const int rr = idx / 18, cc = idx - rr * 18;
            const int gh = h0 - 1 + rr, gw = w0 - 1 + cc;
            float v = 0.f;
            if (gh >= 0 && gh < 64 && gw >= 0 && gw < 64) v = xp[gh * 64 + gw];
            xsf[rr][cc] = v;
        }
        if (tid < 144) {
            const int u = u_index(wl_g, s);
            wsf[wl_c][wl_k] = wrel[((size_t)(wl_co*64+ci)*8+u)*9 + a0*3 + b0];
        }
        __syncthreads();
        float wr[9];
        #pragma unroll
        for (int k=0;k<9;++k) wr[k]=wsf[ch][k];
        float xv[6][6];
        #pragma unroll
        for (int i=0;i<6;++i) for (int j=0;j<6;++j) xv[i][j]=xsf[by+i][bx+j];
        #pragma unroll
        for (int py=0;py<4;++py) for (int px=0;px<4;++px)
            for (int ki=0;ki<3;++ki) for (int kj=0;kj<3;++kj)
                acc[py][px] += xv[py+ki][px+kj]*wr[ki*3+kj];
    }
    const float bv = bias[co];
    float* op = out + (((size_t)(b*64+co)*8+g)*4096);
    #pragma unroll
    for (int py=0;py<4;++py) for (int px=0;px<4;++px)
        op[(h0+by+py)*64 + (w0+bx+px)] = acc[py][px] + bv;
}

// ---------------- launch ----------------
extern "C" void kernel_launch(void* const* d_in, const int* in_sizes, int n_in,
                              void* d_out, int out_size, void* d_ws, size_t ws_size,
                              hipStream_t stream) {
    const float* x    = (const float*)d_in[0];
    const float* wrel = (const float*)d_in[1];
    const float* bias = (const float*)d_in[2];
    float* out        = (float*)d_out;

    if (ws_size >= (size_t)WS_NEEDED) {
        short* xb   = (short*)d_ws;
        short* bank = (short*)((char*)d_ws + XB_BYTES);
        zero_border<<<1040, 256, 0, stream>>>(xb);
        {
            dim3 g(64, 8, 16);
            prep_x2<<<g, 256, 0, stream>>>(x, xb);
        }
        prep_w<<<1152, 256, 0, stream>>>(wrel, bank);
        dim3 grid(8, 8, 16);
        gconv_mfma<<<grid, 256, 0, stream>>>(xb, bank, bias, out);
    } else {
        dim3 grid(16, 32, 16);
        gconv_direct<<<grid, 256, 0, stream>>>(x, wrel, bias, out);
    }
}